// Round 12
// baseline (306.362 us; speedup 1.0000x reference)
//
#include <hip/hip_runtime.h>
#include <stdint.h>

#define IN_F 4096
#define OUT_F 4096
#define NTOK 8192
#define NNZ_CNT 167772

typedef __attribute__((ext_vector_type(4))) float f32x4;
typedef __attribute__((ext_vector_type(8))) __bf16 bf16x8;
typedef __attribute__((ext_vector_type(8))) unsigned short u16x8;

__device__ __forceinline__ unsigned short f2bf(float f) {
  union { float f; unsigned int i; } u; u.f = f;
  unsigned int i = u.i;
  unsigned int r = (i + 0x7FFFu + ((i >> 16) & 1u)) >> 16;  // RNE
  return (unsigned short)r;
}
__device__ __forceinline__ float bf2f(unsigned short h) {
  union { unsigned int i; float f; } u; u.i = ((unsigned int)h) << 16;
  return u.f;
}
__device__ __forceinline__ float sanitize(float f, float lim) {
  if (f >= -lim && f <= lim) return f;
  if (f > lim) return lim;
  if (f < -lim) return -lim;
  return 0.f;  // NaN
}

// ---------------- per-block dtype detect (bf16 buffer -> false, f32 buffer -> true) ----------------
__device__ __forceinline__ bool detect_isf32(const unsigned short* w, int tid, int* sh_cnt) {
  if (tid == 0) *sh_cnt = 0;
  __syncthreads();
  int local = 0;
  if (tid < 256) {
    for (int j = 0; j < 16; ++j) {
      unsigned short u = w[tid * 16 + j];
      int e = (u >> 7) & 0xFF;
      if (u != 0 && e >= 107 && e <= 126) local++;
    }
  }
  atomicAdd(sh_cnt, local);
  __syncthreads();
  return *sh_cnt < 3481;  // <85% plausible-bf16 -> buffer is f32
}

// ---------------- fused prep: xb = bf16(x)  AND  wc = sanitize(decode(bw)) ----------------
__global__ void prep_kernel(const float4* __restrict__ x, u16x8* __restrict__ xb, int n8x,
                            const void* __restrict__ bw, u16x8* __restrict__ wc, int n8w) {
  __shared__ int sh_cnt;
  const bool isf32 = detect_isf32((const unsigned short*)bw, threadIdx.x, &sh_cnt);
  const int stride = gridDim.x * blockDim.x;
  const int i0 = blockIdx.x * blockDim.x + threadIdx.x;
  for (int i = i0; i < n8x; i += stride) {
    float4 v0 = x[i * 2], v1 = x[i * 2 + 1];
    u16x8 o;
    o[0] = f2bf(sanitize(v0.x, 64.f)); o[1] = f2bf(sanitize(v0.y, 64.f));
    o[2] = f2bf(sanitize(v0.z, 64.f)); o[3] = f2bf(sanitize(v0.w, 64.f));
    o[4] = f2bf(sanitize(v1.x, 64.f)); o[5] = f2bf(sanitize(v1.y, 64.f));
    o[6] = f2bf(sanitize(v1.z, 64.f)); o[7] = f2bf(sanitize(v1.w, 64.f));
    xb[i] = o;
  }
  for (int i = i0; i < n8w; i += stride) {
    u16x8 o;
    if (isf32) {
      const float4* s = (const float4*)bw + i * 2;
      float4 v0 = s[0], v1 = s[1];
      o[0] = f2bf(sanitize(v0.x, 1.f)); o[1] = f2bf(sanitize(v0.y, 1.f));
      o[2] = f2bf(sanitize(v0.z, 1.f)); o[3] = f2bf(sanitize(v0.w, 1.f));
      o[4] = f2bf(sanitize(v1.x, 1.f)); o[5] = f2bf(sanitize(v1.y, 1.f));
      o[6] = f2bf(sanitize(v1.z, 1.f)); o[7] = f2bf(sanitize(v1.w, 1.f));
    } else {
      u16x8 v = ((const u16x8*)bw)[i];
#pragma unroll
      for (int j = 0; j < 8; ++j) o[j] = f2bf(sanitize(bf2f(v[j]), 1.f));
    }
    wc[i] = o;
  }
}

// ---------------- sparse residual scatter (self-detecting, CAS for dup (r,c)) ----------------
__global__ void scatter_kernel(const void* __restrict__ vals,
                               const int* __restrict__ rows,
                               const int* __restrict__ cols,
                               unsigned short* __restrict__ W,
                               const void* __restrict__ bw_probe) {
  __shared__ int sh_cnt;
  const bool isf32 = detect_isf32((const unsigned short*)bw_probe, threadIdx.x, &sh_cnt);
  int i = blockIdx.x * blockDim.x + threadIdx.x;
  if (i >= NNZ_CNT) return;
  int r = rows[i], c = cols[i];
  if ((unsigned)r >= OUT_F || (unsigned)c >= IN_F) return;
  float v = isf32 ? ((const float*)vals)[i] : bf2f(((const unsigned short*)vals)[i]);
  v = sanitize(v, 1.f);
  unsigned int* addr = (unsigned int*)(W + (size_t)r * IN_F + (c & ~1));
  bool hi = (c & 1);
  unsigned int old = *addr, assumed;
  do {
    assumed = old;
    unsigned short h = hi ? (unsigned short)(assumed >> 16) : (unsigned short)(assumed & 0xFFFFu);
    unsigned short nh = f2bf(bf2f(h) + v);
    unsigned int nw = hi ? ((assumed & 0x0000FFFFu) | ((unsigned int)nh << 16))
                         : ((assumed & 0xFFFF0000u) | (unsigned int)nh);
    old = atomicCAS(addr, assumed, nw);
  } while (old != assumed);
}

#define GLOAD16(g, l)                                                                  \
  __builtin_amdgcn_global_load_lds((const __attribute__((address_space(1))) void*)(g), \
                                   (__attribute__((address_space(3))) void*)(l), 16, 0, 0)

// ================= 256x256 deep-pipeline bf16 GEMM (r7 champion + 2 sync relaxations) =================
// Identical geometry/staging/swizzle/ledger to round-7/11 champion. Changes (both provable
// relaxations, write-safety barriers untouched):
//  (1) ONE vmcnt per K-tile: at kt-top, in-flight = 12 {H(kt,0),H(kt,1),H(kt+1,0)}; vmcnt(4)
//      drains BOTH halves of kt (each issued >=1 K-tile ago >> HBM latency). The kt-top
//      barrier then publishes kk0 AND kk1 together.
//  (2) kk1 fragment reads hoisted ABOVE the mid-barrier (data already published at kt-top);
//      the mid-barrier remains solely for write-safety of the buf[c].kk0 stages. The P3
//      read-burst now hides under barrier skew; after it, lgkmcnt(0) + 32 back-to-back MFMA.
__global__ __launch_bounds__(512, 2) void gemm256_kernel(
    const unsigned short* __restrict__ Abf,  // x bf16 [NTOK][IN_F]
    const unsigned short* __restrict__ Bw,   // combined W bf16 [OUT_F][IN_F]
    float* __restrict__ C) {
  __shared__ __align__(16) char lds[131072];
  const int t = threadIdx.x;
  const int l = t & 63;
  const int wv = t >> 6;
  const int wm = wv >> 2;   // 0..1
  const int wn = wv & 3;    // 0..3
  const int l15 = l & 15;

  // XCD-bijective swizzle: 512 blocks, 512%8==0, cpx=64
  const int swz = (blockIdx.x & 7) * 64 + (blockIdx.x >> 3);
  const int bm = (swz >> 4) * 256;
  const int bn = (swz & 15) * 256;

  // staging: thread t covers (row=t>>2 within 128-row group, unit=t&3); source pre-swizzled
  const int srow = t >> 2;
  const int sunit = (t & 3) ^ ((t >> 3) & 3);
  const unsigned short* aS0 = Abf + (size_t)(bm + srow) * IN_F + sunit * 8;
  const unsigned short* aS1 = aS0 + (size_t)128 * IN_F;
  const unsigned short* bS0 = Bw + (size_t)(bn + srow) * IN_F + sunit * 8;
  const unsigned short* bS1 = bS0 + (size_t)128 * IN_F;
  char* dstA = (char*)lds + wv * 1024;
  char* dstB = (char*)lds + 32768 + wv * 1024;

  // read-side fragment addressing (16B units); swizzle unit = (l>>4)^((l15>>1)&3)
  const int u = (l >> 4) ^ ((l15 >> 1) & 3);
  const int iA = (wm * 128 + l15) * 4 + u;
  const int iB = 2048 + (wn * 64 + l15) * 4 + u;
  const bf16x8* smp = (const bf16x8*)lds;

  f32x4 acc[8][4] = {};

  // prologue: H(0,0) H(0,1) H(1,0) -> 12 in flight
  GLOAD16(aS0 + 0, dstA + 0);          GLOAD16(aS1 + 0, dstA + 8192);
  GLOAD16(bS0 + 0, dstB + 0);          GLOAD16(bS1 + 0, dstB + 8192);
  GLOAD16(aS0 + 32, dstA + 16384);     GLOAD16(aS1 + 32, dstA + 16384 + 8192);
  GLOAD16(bS0 + 32, dstB + 16384);     GLOAD16(bS1 + 32, dstB + 16384 + 8192);
  GLOAD16(aS0 + 64, dstA + 65536);     GLOAD16(aS1 + 64, dstA + 65536 + 8192);
  GLOAD16(bS0 + 64, dstB + 65536);     GLOAD16(bS1 + 64, dstB + 65536 + 8192);

  for (int kt = 0; kt < 64; ++kt) {
    const int c = kt & 1;
    const int cU = c << 12;
    const int s1 = ((kt + 1 < 64) ? (kt + 1) : 63) * 64 + 32;  // src: (kt+1).kk1
    const int s2 = ((kt + 2 < 64) ? (kt + 2) : 63) * 64;       // src: (kt+2).kk0
    const int d1 = (c ^ 1) * 65536 + 16384;                    // dst: buf c^1, kk1
    const int d2 = c * 65536;                                  // dst: buf c,   kk0
    bf16x8 av[4], bv[4], av1[8], bv1[4];

    // ---- kt-top: single vmcnt + barrier (drains & publishes BOTH halves of kt) ----
    asm volatile("s_waitcnt vmcnt(4)" ::: "memory");
    asm volatile("s_barrier" ::: "memory");

    // P1: kk0, m0-3 + all B(kk0)
#pragma unroll
    for (int mi = 0; mi < 4; ++mi) av[mi] = smp[cU + iA + mi * 64];
#pragma unroll
    for (int ni = 0; ni < 4; ++ni) bv[ni] = smp[cU + iB + ni * 64];
    GLOAD16(aS0 + s1, dstA + d1);
    GLOAD16(aS1 + s1, dstA + d1 + 8192);
    __builtin_amdgcn_s_setprio(1);
#pragma unroll
    for (int mi = 0; mi < 4; ++mi)
#pragma unroll
      for (int ni = 0; ni < 4; ++ni)
        acc[mi][ni] = __builtin_amdgcn_mfma_f32_16x16x32_bf16(av[mi], bv[ni], acc[mi][ni], 0, 0, 0);
    __builtin_amdgcn_s_setprio(0);

    // P2: kk0, m4-7 (B reused in regs)
#pragma unroll
    for (int mi = 0; mi < 4; ++mi) av[mi] = smp[cU + iA + (mi + 4) * 64];
    GLOAD16(bS0 + s1, dstB + d1);
    GLOAD16(bS1 + s1, dstB + d1 + 8192);
    __builtin_amdgcn_s_setprio(1);
#pragma unroll
    for (int mi = 0; mi < 4; ++mi)
#pragma unroll
      for (int ni = 0; ni < 4; ++ni)
        acc[mi + 4][ni] = __builtin_amdgcn_mfma_f32_16x16x32_bf16(av[mi], bv[ni], acc[mi + 4][ni], 0, 0, 0);
    __builtin_amdgcn_s_setprio(0);

    // preread ALL kk1 fragments (published at kt-top barrier; hides under mid-barrier skew)
#pragma unroll
    for (int mi = 0; mi < 8; ++mi) av1[mi] = smp[cU + 1024 + iA + mi * 64];
#pragma unroll
    for (int ni = 0; ni < 4; ++ni) bv1[ni] = smp[cU + 1024 + iB + ni * 64];

    // mid barrier: write-safety for buf[c].kk0 stages only
    asm volatile("s_barrier" ::: "memory");
    asm volatile("s_waitcnt lgkmcnt(0)" ::: "memory");

    // P3: kk1, m0-3
    GLOAD16(aS0 + s2, dstA + d2);
    GLOAD16(aS1 + s2, dstA + d2 + 8192);
    __builtin_amdgcn_s_setprio(1);
#pragma unroll
    for (int mi = 0; mi < 4; ++mi)
#pragma unroll
      for (int ni = 0; ni < 4; ++ni)
        acc[mi][ni] = __builtin_amdgcn_mfma_f32_16x16x32_bf16(av1[mi], bv1[ni], acc[mi][ni], 0, 0, 0);
    __builtin_amdgcn_s_setprio(0);

    // P4: kk1, m4-7
    GLOAD16(bS0 + s2, dstB + d2);
    GLOAD16(bS1 + s2, dstB + d2 + 8192);
    __builtin_amdgcn_s_setprio(1);
#pragma unroll
    for (int mi = 0; mi < 4; ++mi)
#pragma unroll
      for (int ni = 0; ni < 4; ++ni)
        acc[mi + 4][ni] = __builtin_amdgcn_mfma_f32_16x16x32_bf16(av1[mi + 4], bv1[ni], acc[mi + 4][ni], 0, 0, 0);
    __builtin_amdgcn_s_setprio(0);
  }

  // epilogue: C/D map col=lane&15, row=(lane>>4)*4+r (m89-verified)
#pragma unroll
  for (int mi = 0; mi < 8; ++mi) {
#pragma unroll
    for (int ni = 0; ni < 4; ++ni) {
      int row0 = bm + wm * 128 + mi * 16 + ((l >> 4) << 2);
      int col = bn + wn * 64 + ni * 16 + l15;
#pragma unroll
      for (int r = 0; r < 4; ++r)
        C[(size_t)(row0 + r) * OUT_F + col] = acc[mi][ni][r];
    }
  }
}

// ================= m97-style fallback GEMM (ws in [32,96) MiB) =================
__global__ __launch_bounds__(256, 3) void gemm_kernel(
    const float* __restrict__ Af, const unsigned short* __restrict__ Bw, float* __restrict__ C) {
  __shared__ bf16x8 smem[2048];
  const int tid = threadIdx.x;
  const int lane = tid & 63;
  const int wv = tid >> 6;
  const int bm = blockIdx.x * 128;
  const int bn = blockIdx.y * 128;
  const int srow = wv * 8 + (lane >> 3);
  const int scol = (lane & 7) * 8;
  const int wr = wv >> 1, wc = wv & 1;
  f32x4 acc[4][4] = {};
  const float* afp[4];
  const unsigned short* bptr[4];
#pragma unroll
  for (int q = 0; q < 4; ++q) {
    afp[q] = Af + (size_t)(bm + q * 32 + srow) * IN_F + scol;
    bptr[q] = Bw + (size_t)(bn + q * 32 + srow) * IN_F + scol;
  }
  char* smbase = (char*)smem;
  for (int k0 = 0; k0 < IN_F; k0 += 64) {
    __syncthreads();
#pragma unroll
    for (int q = 0; q < 4; ++q)
      GLOAD16(bptr[q] + k0, smbase + 16384 + q * 4096 + wv * 1024);
#pragma unroll
    for (int q = 0; q < 4; ++q) {
      const float* s = afp[q] + k0;
      float4 v0 = ((const float4*)s)[0];
      float4 v1 = ((const float4*)s)[1];
      u16x8 p;
      p[0] = f2bf(sanitize(v0.x, 64.f)); p[1] = f2bf(sanitize(v0.y, 64.f));
      p[2] = f2bf(sanitize(v0.z, 64.f)); p[3] = f2bf(sanitize(v0.w, 64.f));
      p[4] = f2bf(sanitize(v1.x, 64.f)); p[5] = f2bf(sanitize(v1.y, 64.f));
      p[6] = f2bf(sanitize(v1.z, 64.f)); p[7] = f2bf(sanitize(v1.w, 64.f));
      ((u16x8*)smem)[q * 256 + wv * 64 + lane] = p;
    }
    __syncthreads();
#pragma unroll
    for (int kk = 0; kk < 2; ++kk) {
      bf16x8 av[4], bv[4];
#pragma unroll
      for (int m = 0; m < 4; ++m)
        av[m] = smem[(wr * 64 + m * 16 + (lane & 15)) * 8 + kk * 4 + (lane >> 4)];
#pragma unroll
      for (int n = 0; n < 4; ++n)
        bv[n] = smem[1024 + (wc * 64 + n * 16 + (lane & 15)) * 8 + kk * 4 + (lane >> 4)];
#pragma unroll
      for (int m = 0; m < 4; ++m)
#pragma unroll
        for (int n = 0; n < 4; ++n)
          acc[m][n] = __builtin_amdgcn_mfma_f32_16x16x32_bf16(av[m], bv[n], acc[m][n], 0, 0, 0);
    }
  }
#pragma unroll
  for (int m = 0; m < 4; ++m)
#pragma unroll
    for (int n = 0; n < 4; ++n) {
      int row0 = bm + wr * 64 + m * 16 + ((lane >> 4) << 2);
      int col = bn + wc * 64 + n * 16 + (lane & 15);
#pragma unroll
      for (int r = 0; r < 4; ++r)
        C[(size_t)(row0 + r) * OUT_F + col] = acc[m][n][r];
    }
}

// ---------------- naive fallback (ws < 32 MiB), self-detecting ----------------
__global__ void naive_gemm_kernel(const float* __restrict__ x, const void* __restrict__ W,
                                  float* __restrict__ out) {
  __shared__ int sh_cnt;
  const bool isf32 = detect_isf32((const unsigned short*)W, threadIdx.x, &sh_cnt);
  int o = blockIdx.x * 256 + threadIdx.x;
  int t = blockIdx.y;
  const float* xr = x + (size_t)t * IN_F;
  float acc = 0.f;
  if (isf32) {
    const float* wr = (const float*)W + (size_t)o * IN_F;
    for (int k = 0; k < IN_F; ++k) acc += bf2f(f2bf(xr[k])) * bf2f(f2bf(sanitize(wr[k], 1.f)));
  } else {
    const unsigned short* wr = (const unsigned short*)W + (size_t)o * IN_F;
    for (int k = 0; k < IN_F; ++k) acc += bf2f(f2bf(xr[k])) * sanitize(bf2f(wr[k]), 1.f);
  }
  out[(size_t)t * OUT_F + o] = acc;
}
__global__ void naive_sparse_kernel(const float* __restrict__ x, const void* __restrict__ vals,
                                    const int* __restrict__ rows, const int* __restrict__ cols,
                                    float* __restrict__ out, const void* __restrict__ bw_probe) {
  __shared__ int sh_cnt;
  const bool isf32 = detect_isf32((const unsigned short*)bw_probe, threadIdx.x, &sh_cnt);
  int t = blockIdx.x * 256 + threadIdx.x;
  if (t >= NTOK) return;
  const float* xr = x + (size_t)t * IN_F;
  float* orow = out + (size_t)t * OUT_F;
  for (int i = 0; i < NNZ_CNT; ++i) {
    int r = rows[i], c = cols[i];
    if ((unsigned)r >= OUT_F || (unsigned)c >= IN_F) continue;
    float v = isf32 ? ((const float*)vals)[i] : bf2f(((const unsigned short*)vals)[i]);
    orow[r] += sanitize(v, 1.f) * xr[c];
  }
}

extern "C" void kernel_launch(void* const* d_in, const int* in_sizes, int n_in,
                              void* d_out, int out_size, void* d_ws, size_t ws_size,
                              hipStream_t stream) {
  (void)out_size;
  const int NX = NTOK * IN_F, NW = OUT_F * IN_F;
  int ix = -1, ib = -1, qs[3], nq = 0;
  for (int i = 0; i < n_in; ++i) {
    if (in_sizes[i] == NX) ix = i;
    else if (in_sizes[i] == NW) ib = i;
    else if (in_sizes[i] == NNZ_CNT && nq < 3) qs[nq++] = i;
  }
  if (ix < 0 || ib < 0 || nq < 3) { ix = 0; ib = 1; qs[0] = 2; qs[1] = 3; qs[2] = 4; }
  const float* x = (const float*)d_in[ix];
  const void* bw = d_in[ib];
  const int* rows = (const int*)d_in[qs[1]];
  const void* vals;
  const int* cols;
  if (ix < ib) { vals = d_in[qs[0]]; cols = (const int*)d_in[qs[2]]; }
  else         { vals = d_in[qs[2]]; cols = (const int*)d_in[qs[0]]; }
  float* out = (float*)d_out;

  const size_t w_bytes = (size_t)OUT_F * IN_F * 2;    // 32 MiB
  const size_t xb_bytes = (size_t)NTOK * IN_F * 2;    // 64 MiB

  if (ws_size < w_bytes + 64) {  // naive path
    hipLaunchKernelGGL(naive_gemm_kernel, dim3(OUT_F / 256, NTOK), dim3(256), 0, stream,
                       x, bw, out);
    hipLaunchKernelGGL(naive_sparse_kernel, dim3((NTOK + 255) / 256), dim3(256), 0, stream,
                       x, vals, rows, cols, out, bw);
    return;
  }

  unsigned short* wcmb = (unsigned short*)d_ws;
  const bool big = ws_size >= w_bytes + xb_bytes;
  unsigned short* xb = (unsigned short*)((char*)d_ws + w_bytes);

  hipLaunchKernelGGL(prep_kernel, dim3(2048), dim3(256), 0, stream,
                     (const float4*)x, (u16x8*)xb, big ? (NX / 8) : 0,
                     bw, (u16x8*)wcmb, NW / 8);
  hipLaunchKernelGGL(scatter_kernel, dim3((NNZ_CNT + 255) / 256), dim3(256), 0, stream,
                     vals, rows, cols, wcmb, bw);

  if (big) {
    hipLaunchKernelGGL(gemm256_kernel, dim3((NTOK / 256) * (OUT_F / 256)), dim3(512), 0, stream,
                       xb, wcmb, out);
  } else {
    hipLaunchKernelGGL(gemm_kernel, dim3(NTOK / 128, OUT_F / 128), dim3(256), 0, stream,
                       x, wcmb, out);
  }
}

// Round 13
// 303.317 us; speedup vs baseline: 1.0100x; 1.0100x over previous
//
#include <hip/hip_runtime.h>
#include <stdint.h>

#define IN_F 4096
#define OUT_F 4096
#define NTOK 8192
#define NNZ_CNT 167772

typedef __attribute__((ext_vector_type(4))) float f32x4;
typedef __attribute__((ext_vector_type(8))) __bf16 bf16x8;
typedef __attribute__((ext_vector_type(8))) unsigned short u16x8;

__device__ __forceinline__ unsigned short f2bf(float f) {
  union { float f; unsigned int i; } u; u.f = f;
  unsigned int i = u.i;
  unsigned int r = (i + 0x7FFFu + ((i >> 16) & 1u)) >> 16;  // RNE
  return (unsigned short)r;
}
__device__ __forceinline__ float bf2f(unsigned short h) {
  union { unsigned int i; float f; } u; u.i = ((unsigned int)h) << 16;
  return u.f;
}
__device__ __forceinline__ float sanitize(float f, float lim) {
  if (f >= -lim && f <= lim) return f;
  if (f > lim) return lim;
  if (f < -lim) return -lim;
  return 0.f;  // NaN
}

// ---------------- per-block dtype detect (bf16 buffer -> false, f32 buffer -> true) ----------------
__device__ __forceinline__ bool detect_isf32(const unsigned short* w, int tid, int* sh_cnt) {
  if (tid == 0) *sh_cnt = 0;
  __syncthreads();
  int local = 0;
  if (tid < 256) {
    for (int j = 0; j < 16; ++j) {
      unsigned short u = w[tid * 16 + j];
      int e = (u >> 7) & 0xFF;
      if (u != 0 && e >= 107 && e <= 126) local++;
    }
  }
  atomicAdd(sh_cnt, local);
  __syncthreads();
  return *sh_cnt < 3481;  // <85% plausible-bf16 -> buffer is f32
}

// ---------------- fused prep: xb = bf16(x)  AND  wc = sanitize(decode(bw)) ----------------
__global__ void prep_kernel(const float4* __restrict__ x, u16x8* __restrict__ xb, int n8x,
                            const void* __restrict__ bw, u16x8* __restrict__ wc, int n8w) {
  __shared__ int sh_cnt;
  const bool isf32 = detect_isf32((const unsigned short*)bw, threadIdx.x, &sh_cnt);
  const int stride = gridDim.x * blockDim.x;
  const int i0 = blockIdx.x * blockDim.x + threadIdx.x;
  for (int i = i0; i < n8x; i += stride) {
    float4 v0 = x[i * 2], v1 = x[i * 2 + 1];
    u16x8 o;
    o[0] = f2bf(sanitize(v0.x, 64.f)); o[1] = f2bf(sanitize(v0.y, 64.f));
    o[2] = f2bf(sanitize(v0.z, 64.f)); o[3] = f2bf(sanitize(v0.w, 64.f));
    o[4] = f2bf(sanitize(v1.x, 64.f)); o[5] = f2bf(sanitize(v1.y, 64.f));
    o[6] = f2bf(sanitize(v1.z, 64.f)); o[7] = f2bf(sanitize(v1.w, 64.f));
    xb[i] = o;
  }
  for (int i = i0; i < n8w; i += stride) {
    u16x8 o;
    if (isf32) {
      const float4* s = (const float4*)bw + i * 2;
      float4 v0 = s[0], v1 = s[1];
      o[0] = f2bf(sanitize(v0.x, 1.f)); o[1] = f2bf(sanitize(v0.y, 1.f));
      o[2] = f2bf(sanitize(v0.z, 1.f)); o[3] = f2bf(sanitize(v0.w, 1.f));
      o[4] = f2bf(sanitize(v1.x, 1.f)); o[5] = f2bf(sanitize(v1.y, 1.f));
      o[6] = f2bf(sanitize(v1.z, 1.f)); o[7] = f2bf(sanitize(v1.w, 1.f));
    } else {
      u16x8 v = ((const u16x8*)bw)[i];
#pragma unroll
      for (int j = 0; j < 8; ++j) o[j] = f2bf(sanitize(bf2f(v[j]), 1.f));
    }
    wc[i] = o;
  }
}

// ---------------- sparse residual scatter (self-detecting, CAS for dup (r,c)) ----------------
__global__ void scatter_kernel(const void* __restrict__ vals,
                               const int* __restrict__ rows,
                               const int* __restrict__ cols,
                               unsigned short* __restrict__ W,
                               const void* __restrict__ bw_probe) {
  __shared__ int sh_cnt;
  const bool isf32 = detect_isf32((const unsigned short*)bw_probe, threadIdx.x, &sh_cnt);
  int i = blockIdx.x * blockDim.x + threadIdx.x;
  if (i >= NNZ_CNT) return;
  int r = rows[i], c = cols[i];
  if ((unsigned)r >= OUT_F || (unsigned)c >= IN_F) return;
  float v = isf32 ? ((const float*)vals)[i] : bf2f(((const unsigned short*)vals)[i]);
  v = sanitize(v, 1.f);
  unsigned int* addr = (unsigned int*)(W + (size_t)r * IN_F + (c & ~1));
  bool hi = (c & 1);
  unsigned int old = *addr, assumed;
  do {
    assumed = old;
    unsigned short h = hi ? (unsigned short)(assumed >> 16) : (unsigned short)(assumed & 0xFFFFu);
    unsigned short nh = f2bf(bf2f(h) + v);
    unsigned int nw = hi ? ((assumed & 0x0000FFFFu) | ((unsigned int)nh << 16))
                         : ((assumed & 0xFFFF0000u) | (unsigned int)nh);
    old = atomicCAS(addr, assumed, nw);
  } while (old != assumed);
}

#define GLOAD16(g, l)                                                                  \
  __builtin_amdgcn_global_load_lds((const __attribute__((address_space(1))) void*)(g), \
                                   (__attribute__((address_space(3))) void*)(l), 16, 0, 0)

// ================= 256x256 deep-pipeline bf16 GEMM (r7 champion, 2x K-tile unroll) =================
// Instruction sequence per K-tile is IDENTICAL to the round-7/11 champion (same reads, same
// stage order, same vmcnt(8)+barrier ledger). Only change: manual 2x unroll of the kt loop so
// the double-buffer index c is compile-time (cU=0 / cU=4096) -> all LDS addresses fold to
// base+immediate, deleting the per-iteration c/cU/d1/d2 VALU arithmetic.
__global__ __launch_bounds__(512, 2) void gemm256_kernel(
    const unsigned short* __restrict__ Abf,  // x bf16 [NTOK][IN_F]
    const unsigned short* __restrict__ Bw,   // combined W bf16 [OUT_F][IN_F]
    float* __restrict__ C) {
  __shared__ __align__(16) char lds[131072];
  const int t = threadIdx.x;
  const int l = t & 63;
  const int wv = t >> 6;
  const int wm = wv >> 2;   // 0..1
  const int wn = wv & 3;    // 0..3
  const int l15 = l & 15;

  // XCD-bijective swizzle: 512 blocks, 512%8==0, cpx=64
  const int swz = (blockIdx.x & 7) * 64 + (blockIdx.x >> 3);
  const int bm = (swz >> 4) * 256;
  const int bn = (swz & 15) * 256;

  // staging: thread t covers (row=t>>2 within 128-row group, unit=t&3); source pre-swizzled
  const int srow = t >> 2;
  const int sunit = (t & 3) ^ ((t >> 3) & 3);
  const unsigned short* aS0 = Abf + (size_t)(bm + srow) * IN_F + sunit * 8;
  const unsigned short* aS1 = aS0 + (size_t)128 * IN_F;
  const unsigned short* bS0 = Bw + (size_t)(bn + srow) * IN_F + sunit * 8;
  const unsigned short* bS1 = bS0 + (size_t)128 * IN_F;
  char* dstA = (char*)lds + wv * 1024;
  char* dstB = (char*)lds + 32768 + wv * 1024;

  // read-side fragment addressing (16B units); swizzle unit = (l>>4)^((l15>>1)&3)
  const int u = (l >> 4) ^ ((l15 >> 1) & 3);
  const int iA = (wm * 128 + l15) * 4 + u;
  const int iB = 2048 + (wn * 64 + l15) * 4 + u;
  const bf16x8* smp = (const bf16x8*)lds;

  f32x4 acc[8][4] = {};

  // prologue: H(0,0) H(0,1) H(1,0) -> 12 in flight
  GLOAD16(aS0 + 0, dstA + 0);          GLOAD16(aS1 + 0, dstA + 8192);
  GLOAD16(bS0 + 0, dstB + 0);          GLOAD16(bS1 + 0, dstB + 8192);
  GLOAD16(aS0 + 32, dstA + 16384);     GLOAD16(aS1 + 32, dstA + 16384 + 8192);
  GLOAD16(bS0 + 32, dstB + 16384);     GLOAD16(bS1 + 32, dstB + 16384 + 8192);
  GLOAD16(aS0 + 64, dstA + 65536);     GLOAD16(aS1 + 64, dstA + 65536 + 8192);
  GLOAD16(bS0 + 64, dstB + 65536);     GLOAD16(bS1 + 64, dstB + 65536 + 8192);

  // K-tile body; CU_, D1_, D2_ are compile-time constants after 2x unroll.
#define KTILE_BODY(CU_, D1_, D2_, S1_, S2_)                                                    \
  {                                                                                            \
    bf16x8 av[4], bv[4];                                                                       \
    asm volatile("s_waitcnt vmcnt(8)" ::: "memory");                                           \
    asm volatile("s_barrier" ::: "memory");                                                    \
    _Pragma("unroll")                                                                          \
    for (int mi = 0; mi < 4; ++mi) av[mi] = smp[(CU_) + iA + mi * 64];                         \
    _Pragma("unroll")                                                                          \
    for (int ni = 0; ni < 4; ++ni) bv[ni] = smp[(CU_) + iB + ni * 64];                         \
    GLOAD16(aS0 + (S1_), dstA + (D1_));                                                        \
    GLOAD16(aS1 + (S1_), dstA + (D1_) + 8192);                                                 \
    __builtin_amdgcn_s_setprio(1);                                                             \
    _Pragma("unroll")                                                                          \
    for (int mi = 0; mi < 4; ++mi)                                                             \
      _Pragma("unroll")                                                                        \
      for (int ni = 0; ni < 4; ++ni)                                                           \
        acc[mi][ni] = __builtin_amdgcn_mfma_f32_16x16x32_bf16(av[mi], bv[ni], acc[mi][ni], 0, 0, 0); \
    __builtin_amdgcn_s_setprio(0);                                                             \
    _Pragma("unroll")                                                                          \
    for (int mi = 0; mi < 4; ++mi) av[mi] = smp[(CU_) + iA + (mi + 4) * 64];                   \
    GLOAD16(bS0 + (S1_), dstB + (D1_));                                                        \
    GLOAD16(bS1 + (S1_), dstB + (D1_) + 8192);                                                 \
    __builtin_amdgcn_s_setprio(1);                                                             \
    _Pragma("unroll")                                                                          \
    for (int mi = 0; mi < 4; ++mi)                                                             \
      _Pragma("unroll")                                                                        \
      for (int ni = 0; ni < 4; ++ni)                                                           \
        acc[mi + 4][ni] = __builtin_amdgcn_mfma_f32_16x16x32_bf16(av[mi], bv[ni], acc[mi + 4][ni], 0, 0, 0); \
    __builtin_amdgcn_s_setprio(0);                                                             \
    asm volatile("s_waitcnt vmcnt(8)" ::: "memory");                                           \
    asm volatile("s_barrier" ::: "memory");                                                    \
    _Pragma("unroll")                                                                          \
    for (int mi = 0; mi < 4; ++mi) av[mi] = smp[(CU_) + 1024 + iA + mi * 64];                  \
    _Pragma("unroll")                                                                          \
    for (int ni = 0; ni < 4; ++ni) bv[ni] = smp[(CU_) + 1024 + iB + ni * 64];                  \
    GLOAD16(aS0 + (S2_), dstA + (D2_));                                                        \
    GLOAD16(aS1 + (S2_), dstA + (D2_) + 8192);                                                 \
    __builtin_amdgcn_s_setprio(1);                                                             \
    _Pragma("unroll")                                                                          \
    for (int mi = 0; mi < 4; ++mi)                                                             \
      _Pragma("unroll")                                                                        \
      for (int ni = 0; ni < 4; ++ni)                                                           \
        acc[mi][ni] = __builtin_amdgcn_mfma_f32_16x16x32_bf16(av[mi], bv[ni], acc[mi][ni], 0, 0, 0); \
    __builtin_amdgcn_s_setprio(0);                                                             \
    _Pragma("unroll")                                                                          \
    for (int mi = 0; mi < 4; ++mi) av[mi] = smp[(CU_) + 1024 + iA + (mi + 4) * 64];            \
    GLOAD16(bS0 + (S2_), dstB + (D2_));                                                        \
    GLOAD16(bS1 + (S2_), dstB + (D2_) + 8192);                                                 \
    __builtin_amdgcn_s_setprio(1);                                                             \
    _Pragma("unroll")                                                                          \
    for (int mi = 0; mi < 4; ++mi)                                                             \
      _Pragma("unroll")                                                                        \
      for (int ni = 0; ni < 4; ++ni)                                                           \
        acc[mi + 4][ni] = __builtin_amdgcn_mfma_f32_16x16x32_bf16(av[mi], bv[ni], acc[mi + 4][ni], 0, 0, 0); \
    __builtin_amdgcn_s_setprio(0);                                                             \
  }

  for (int kt = 0; kt < 64; kt += 2) {
    // even K-tile: c=0 (cU=0, d1=buf1.kk1=65536+16384, d2=buf0.kk0=0)
    const int s1a = (kt + 1) * 64 + 32;                        // kt+1 <= 63 always (kt even)
    const int s2a = ((kt + 2 < 64) ? (kt + 2) : 63) * 64;
    KTILE_BODY(0, 65536 + 16384, 0, s1a, s2a)
    // odd K-tile: c=1 (cU=4096 units, d1=buf0.kk1=16384, d2=buf1.kk0=65536)
    const int s1b = ((kt + 2 < 64) ? (kt + 2) : 63) * 64 + 32;
    const int s2b = ((kt + 3 < 64) ? (kt + 3) : 63) * 64;
    KTILE_BODY(4096, 16384, 65536, s1b, s2b)
  }
#undef KTILE_BODY

  // epilogue: C/D map col=lane&15, row=(lane>>4)*4+r (m89-verified)
#pragma unroll
  for (int mi = 0; mi < 8; ++mi) {
#pragma unroll
    for (int ni = 0; ni < 4; ++ni) {
      int row0 = bm + wm * 128 + mi * 16 + ((l >> 4) << 2);
      int col = bn + wn * 64 + ni * 16 + l15;
#pragma unroll
      for (int r = 0; r < 4; ++r)
        C[(size_t)(row0 + r) * OUT_F + col] = acc[mi][ni][r];
    }
  }
}

// ================= m97-style fallback GEMM (ws in [32,96) MiB) =================
__global__ __launch_bounds__(256, 3) void gemm_kernel(
    const float* __restrict__ Af, const unsigned short* __restrict__ Bw, float* __restrict__ C) {
  __shared__ bf16x8 smem[2048];
  const int tid = threadIdx.x;
  const int lane = tid & 63;
  const int wv = tid >> 6;
  const int bm = blockIdx.x * 128;
  const int bn = blockIdx.y * 128;
  const int srow = wv * 8 + (lane >> 3);
  const int scol = (lane & 7) * 8;
  const int wr = wv >> 1, wc = wv & 1;
  f32x4 acc[4][4] = {};
  const float* afp[4];
  const unsigned short* bptr[4];
#pragma unroll
  for (int q = 0; q < 4; ++q) {
    afp[q] = Af + (size_t)(bm + q * 32 + srow) * IN_F + scol;
    bptr[q] = Bw + (size_t)(bn + q * 32 + srow) * IN_F + scol;
  }
  char* smbase = (char*)smem;
  for (int k0 = 0; k0 < IN_F; k0 += 64) {
    __syncthreads();
#pragma unroll
    for (int q = 0; q < 4; ++q)
      GLOAD16(bptr[q] + k0, smbase + 16384 + q * 4096 + wv * 1024);
#pragma unroll
    for (int q = 0; q < 4; ++q) {
      const float* s = afp[q] + k0;
      float4 v0 = ((const float4*)s)[0];
      float4 v1 = ((const float4*)s)[1];
      u16x8 p;
      p[0] = f2bf(sanitize(v0.x, 64.f)); p[1] = f2bf(sanitize(v0.y, 64.f));
      p[2] = f2bf(sanitize(v0.z, 64.f)); p[3] = f2bf(sanitize(v0.w, 64.f));
      p[4] = f2bf(sanitize(v1.x, 64.f)); p[5] = f2bf(sanitize(v1.y, 64.f));
      p[6] = f2bf(sanitize(v1.z, 64.f)); p[7] = f2bf(sanitize(v1.w, 64.f));
      ((u16x8*)smem)[q * 256 + wv * 64 + lane] = p;
    }
    __syncthreads();
#pragma unroll
    for (int kk = 0; kk < 2; ++kk) {
      bf16x8 av[4], bv[4];
#pragma unroll
      for (int m = 0; m < 4; ++m)
        av[m] = smem[(wr * 64 + m * 16 + (lane & 15)) * 8 + kk * 4 + (lane >> 4)];
#pragma unroll
      for (int n = 0; n < 4; ++n)
        bv[n] = smem[1024 + (wc * 64 + n * 16 + (lane & 15)) * 8 + kk * 4 + (lane >> 4)];
#pragma unroll
      for (int m = 0; m < 4; ++m)
#pragma unroll
        for (int n = 0; n < 4; ++n)
          acc[m][n] = __builtin_amdgcn_mfma_f32_16x16x32_bf16(av[m], bv[n], acc[m][n], 0, 0, 0);
    }
  }
#pragma unroll
  for (int m = 0; m < 4; ++m)
#pragma unroll
    for (int n = 0; n < 4; ++n) {
      int row0 = bm + wr * 64 + m * 16 + ((lane >> 4) << 2);
      int col = bn + wc * 64 + n * 16 + (lane & 15);
#pragma unroll
      for (int r = 0; r < 4; ++r)
        C[(size_t)(row0 + r) * OUT_F + col] = acc[m][n][r];
    }
}

// ---------------- naive fallback (ws < 32 MiB), self-detecting ----------------
__global__ void naive_gemm_kernel(const float* __restrict__ x, const void* __restrict__ W,
                                  float* __restrict__ out) {
  __shared__ int sh_cnt;
  const bool isf32 = detect_isf32((const unsigned short*)W, threadIdx.x, &sh_cnt);
  int o = blockIdx.x * 256 + threadIdx.x;
  int t = blockIdx.y;
  const float* xr = x + (size_t)t * IN_F;
  float acc = 0.f;
  if (isf32) {
    const float* wr = (const float*)W + (size_t)o * IN_F;
    for (int k = 0; k < IN_F; ++k) acc += bf2f(f2bf(xr[k])) * bf2f(f2bf(sanitize(wr[k], 1.f)));
  } else {
    const unsigned short* wr = (const unsigned short*)W + (size_t)o * IN_F;
    for (int k = 0; k < IN_F; ++k) acc += bf2f(f2bf(xr[k])) * sanitize(bf2f(wr[k]), 1.f);
  }
  out[(size_t)t * OUT_F + o] = acc;
}
__global__ void naive_sparse_kernel(const float* __restrict__ x, const void* __restrict__ vals,
                                    const int* __restrict__ rows, const int* __restrict__ cols,
                                    float* __restrict__ out, const void* __restrict__ bw_probe) {
  __shared__ int sh_cnt;
  const bool isf32 = detect_isf32((const unsigned short*)bw_probe, threadIdx.x, &sh_cnt);
  int t = blockIdx.x * 256 + threadIdx.x;
  if (t >= NTOK) return;
  const float* xr = x + (size_t)t * IN_F;
  float* orow = out + (size_t)t * OUT_F;
  for (int i = 0; i < NNZ_CNT; ++i) {
    int r = rows[i], c = cols[i];
    if ((unsigned)r >= OUT_F || (unsigned)c >= IN_F) continue;
    float v = isf32 ? ((const float*)vals)[i] : bf2f(((const unsigned short*)vals)[i]);
    orow[r] += sanitize(v, 1.f) * xr[c];
  }
}

extern "C" void kernel_launch(void* const* d_in, const int* in_sizes, int n_in,
                              void* d_out, int out_size, void* d_ws, size_t ws_size,
                              hipStream_t stream) {
  (void)out_size;
  const int NX = NTOK * IN_F, NW = OUT_F * IN_F;
  int ix = -1, ib = -1, qs[3], nq = 0;
  for (int i = 0; i < n_in; ++i) {
    if (in_sizes[i] == NX) ix = i;
    else if (in_sizes[i] == NW) ib = i;
    else if (in_sizes[i] == NNZ_CNT && nq < 3) qs[nq++] = i;
  }
  if (ix < 0 || ib < 0 || nq < 3) { ix = 0; ib = 1; qs[0] = 2; qs[1] = 3; qs[2] = 4; }
  const float* x = (const float*)d_in[ix];
  const void* bw = d_in[ib];
  const int* rows = (const int*)d_in[qs[1]];
  const void* vals;
  const int* cols;
  if (ix < ib) { vals = d_in[qs[0]]; cols = (const int*)d_in[qs[2]]; }
  else         { vals = d_in[qs[2]]; cols = (const int*)d_in[qs[0]]; }
  float* out = (float*)d_out;

  const size_t w_bytes = (size_t)OUT_F * IN_F * 2;    // 32 MiB
  const size_t xb_bytes = (size_t)NTOK * IN_F * 2;    // 64 MiB

  if (ws_size < w_bytes + 64) {  // naive path
    hipLaunchKernelGGL(naive_gemm_kernel, dim3(OUT_F / 256, NTOK), dim3(256), 0, stream,
                       x, bw, out);
    hipLaunchKernelGGL(naive_sparse_kernel, dim3((NTOK + 255) / 256), dim3(256), 0, stream,
                       x, vals, rows, cols, out, bw);
    return;
  }

  unsigned short* wcmb = (unsigned short*)d_ws;
  const bool big = ws_size >= w_bytes + xb_bytes;
  unsigned short* xb = (unsigned short*)((char*)d_ws + w_bytes);

  hipLaunchKernelGGL(prep_kernel, dim3(2048), dim3(256), 0, stream,
                     (const float4*)x, (u16x8*)xb, big ? (NX / 8) : 0,
                     bw, (u16x8*)wcmb, NW / 8);
  hipLaunchKernelGGL(scatter_kernel, dim3((NNZ_CNT + 255) / 256), dim3(256), 0, stream,
                     vals, rows, cols, wcmb, bw);

  if (big) {
    hipLaunchKernelGGL(gemm256_kernel, dim3((NTOK / 256) * (OUT_F / 256)), dim3(512), 0, stream,
                       xb, wcmb, out);
  } else {
    hipLaunchKernelGGL(gemm_kernel, dim3(NTOK / 128, OUT_F / 128), dim3(256), 0, stream,
                       x, wcmb, out);
  }
}